// Round 1
// baseline (117.795 us; speedup 1.0000x reference)
//
#include <hip/hip_runtime.h>
#include <hip/hip_bf16.h>
#include <math.h>

#define NB    4
#define NC    128
#define NH    56
#define NW    56
#define HP    62
#define NPIX  3136      // 56*56
#define NPPIX 3844      // 62*62
#define CHW   401408    // 128*3136
#define CPHW  492032    // 128*3844
#define KPAD_N 1968128  // 4*128*3844
#define SKSTRIDE 68     // padded LDS row stride for K/V images

// ---------------- prep: bias-fill padded K/V, transpose weights, rel sums ---
__global__ __launch_bounds__(256) void prep_kernel(
    const float* __restrict__ qw, const float* __restrict__ kw,
    const float* __restrict__ vw, const float* __restrict__ kb,
    const float* __restrict__ vb, const float* __restrict__ rel_h,
    const float* __restrict__ rel_w,
    float* __restrict__ kpad, float* __restrict__ vpad,
    float* __restrict__ wTq, float* __restrict__ wTk, float* __restrict__ wTv,
    float* __restrict__ rb)
{
    int idx = blockIdx.x * 256 + threadIdx.x;
    if (idx < KPAD_N) {
        int ch = (idx / NPPIX) & 127;
        kpad[idx] = kb[ch];
        vpad[idx] = vb[ch];
    }
    if (idx < 3 * 16384) {
        int m = idx >> 14;
        int r = idx & 16383;
        int o = r >> 7, c = r & 127;
        const float* src = (m == 0) ? qw : (m == 1) ? kw : vw;
        float* dst = (m == 0) ? wTq : (m == 1) ? wTk : wTv;
        dst[c * 128 + o] = src[o * 128 + c];
    }
    if (idx < 14) {
        const float* src = (idx < 7) ? rel_h : rel_w;
        int off = (idx < 7) ? idx : idx - 7;
        float s = 0.f;
        for (int c = 0; c < 64; ++c) s += src[c * 7 + off];
        rb[idx] = s;
    }
}

// ---------------- conv: fused 1x1 convs Q,K,V (inner region) ---------------
__global__ __launch_bounds__(256) void conv_kernel(
    const float* __restrict__ x,
    const float* __restrict__ wTq, const float* __restrict__ wTk,
    const float* __restrict__ wTv,
    const float* __restrict__ qb, const float* __restrict__ kb,
    const float* __restrict__ vb,
    float* __restrict__ q, float* __restrict__ kpad, float* __restrict__ vpad)
{
    __shared__ float sx[128 * 56];
    int bid = blockIdx.x;
    int osplit = bid & 1;
    int y = (bid >> 1) % 56;
    int b = bid / 112;
    const float* xb = x + b * CHW + y * 56;
    for (int i = threadIdx.x; i < 128 * 56; i += 256) {
        int c = i / 56;
        sx[i] = xb[c * NPIX + (i - c * 56)];
    }
    __syncthreads();
    if (threadIdx.x >= 224) return;
    int xg = threadIdx.x % 14;
    int og = threadIdx.x / 14;
    int o0 = osplit * 64 + og * 4;

    float aq[4][4] = {}, ak[4][4] = {}, av[4][4] = {};
    #pragma unroll 2
    for (int c = 0; c < 128; ++c) {
        float4 xv4 = *(const float4*)&sx[c * 56 + xg * 4];
        float4 wq4 = *(const float4*)&wTq[c * 128 + o0];
        float4 wk4 = *(const float4*)&wTk[c * 128 + o0];
        float4 wv4 = *(const float4*)&wTv[c * 128 + o0];
        float xr[4] = {xv4.x, xv4.y, xv4.z, xv4.w};
        float qr[4] = {wq4.x, wq4.y, wq4.z, wq4.w};
        float kr[4] = {wk4.x, wk4.y, wk4.z, wk4.w};
        float vr[4] = {wv4.x, wv4.y, wv4.z, wv4.w};
        #pragma unroll
        for (int oi = 0; oi < 4; ++oi)
            #pragma unroll
            for (int xi = 0; xi < 4; ++xi) {
                aq[oi][xi] += qr[oi] * xr[xi];
                ak[oi][xi] += kr[oi] * xr[xi];
                av[oi][xi] += vr[oi] * xr[xi];
            }
    }
    #pragma unroll
    for (int oi = 0; oi < 4; ++oi) {
        int o = o0 + oi;
        float bq = qb[o], bk = kb[o], bv = vb[o];
        float* qdst = q + b * CHW + o * NPIX + y * 56 + xg * 4;
        float4 qv4 = {aq[oi][0] + bq, aq[oi][1] + bq, aq[oi][2] + bq, aq[oi][3] + bq};
        *(float4*)qdst = qv4;
        float* kdst = kpad + b * CPHW + o * NPPIX + (y + 3) * 62 + xg * 4 + 3;
        float* vdst = vpad + b * CPHW + o * NPPIX + (y + 3) * 62 + xg * 4 + 3;
        #pragma unroll
        for (int xi = 0; xi < 4; ++xi) {
            kdst[xi] = ak[oi][xi] + bk;
            vdst[xi] = av[oi][xi] + bv;
        }
    }
}

// ---------------- attn: per-(b,c) local attention -------------------------
__global__ __launch_bounds__(256) void attn_kernel(
    const float* __restrict__ q, const float* __restrict__ kpad,
    const float* __restrict__ vpad, const float* __restrict__ rb,
    float* __restrict__ out)
{
    __shared__ float sQ[NPIX];
    __shared__ float sK[62 * SKSTRIDE];
    __shared__ float sV[62 * SKSTRIDE];
    int bc = blockIdx.x;
    const float* qc = q + bc * NPIX;
    const float* kc = kpad + (size_t)bc * NPPIX;
    const float* vc = vpad + (size_t)bc * NPPIX;
    float* oc = out + bc * NPIX;

    for (int i = threadIdx.x; i < NPIX / 4; i += 256)
        ((float4*)sQ)[i] = ((const float4*)qc)[i];
    for (int i = threadIdx.x; i < NPPIX; i += 256) {
        int yy = i / 62;
        int xx = i - yy * 62;
        sK[yy * SKSTRIDE + xx] = kc[i];
        sV[yy * SKSTRIDE + xx] = vc[i];
    }
    __syncthreads();

    int lane = threadIdx.x & 63;
    int wave = threadIdx.x >> 6;
    int k2 = (lane < 49) ? lane : 48;
    int di = k2 / 7, dj = k2 - (k2 / 7) * 7;
    float rbias = rb[di] + rb[7 + dj];
    int koff = di * SKSTRIDE + dj;
    int t16 = lane & 15, p = lane >> 4;
    // PV per-lane precompute
    int kk0 = p * 13;
    int dj0 = kk0 % 7;
    int rel0 = (kk0 / 7) * SKSTRIDE + dj0;
    int nk = (p == 3) ? 10 : 13;

    for (int gi = 0; gi < 49; ++gi) {
        int g = wave * 49 + gi;
        int u0 = g * 16;
        int y0 = u0 / 56;
        int x0 = u0 - y0 * 56;

        // --- qk: 49 lanes, 16 MACs each -------------------------------
        float acc = 0.f, qs = 0.f;
        int base = y0 * SKSTRIDE + x0;
        int xcur = x0;
        #pragma unroll
        for (int t = 0; t < 16; ++t) {
            float qv = sQ[u0 + t];
            qs += qv;
            acc += qv * sK[base + koff];
            int wrap = (xcur == 55);
            base += wrap ? (SKSTRIDE - 55) : 1;
            xcur = wrap ? 0 : (xcur + 1);
        }
        float val = (lane < 49) ? (acc + qs * rbias) : -1e30f;

        // --- softmax over 49 (wave-wide shfl reduce) ------------------
        float m = val;
        #pragma unroll
        for (int off = 32; off >= 1; off >>= 1)
            m = fmaxf(m, __shfl_xor(m, off));
        float e = (lane < 49) ? __expf(val - m) : 0.f;
        float s = e;
        #pragma unroll
        for (int off = 32; off >= 1; off >>= 1)
            s += __shfl_xor(s, off);
        float wv = __fdividef(e, s);

        // --- PV: lanes = 16 t x 4 k-chunks ----------------------------
        int u = u0 + t16;
        int yt = u / 56;
        int xt = u - yt * 56;
        int voff = yt * SKSTRIDE + xt + rel0;
        int djc = dj0;
        float oacc = 0.f;
        #pragma unroll
        for (int k2i = 0; k2i < 13; ++k2i) {
            float wk = __shfl(wv, kk0 + k2i);
            if (k2i < nk) oacc += wk * sV[voff];
            int wrap = (djc == 6);
            voff += wrap ? (SKSTRIDE - 6) : 1;
            djc = wrap ? 0 : (djc + 1);
        }
        oacc += __shfl_xor(oacc, 16);
        oacc += __shfl_xor(oacc, 32);
        if (lane < 16) oc[u0 + lane] = oacc;
    }
}

extern "C" void kernel_launch(void* const* d_in, const int* in_sizes, int n_in,
                              void* d_out, int out_size, void* d_ws, size_t ws_size,
                              hipStream_t stream) {
    const float* x     = (const float*)d_in[0];
    const float* qw    = (const float*)d_in[1];
    const float* qb    = (const float*)d_in[2];
    const float* kw    = (const float*)d_in[3];
    const float* kb    = (const float*)d_in[4];
    const float* vw    = (const float*)d_in[5];
    const float* vb    = (const float*)d_in[6];
    const float* rel_h = (const float*)d_in[7];
    const float* rel_w = (const float*)d_in[8];
    float* out = (float*)d_out;

    float* ws   = (float*)d_ws;
    float* kpad = ws;                    // 1968128
    float* vpad = kpad + KPAD_N;         // 1968128
    float* qbuf = vpad + KPAD_N;         // 1605632
    float* wTq  = qbuf + 1605632;        // 16384
    float* wTk  = wTq + 16384;
    float* wTv  = wTk + 16384;
    float* rb   = wTv + 16384;           // 16

    prep_kernel<<<KPAD_N / 256, 256, 0, stream>>>(qw, kw, vw, kb, vb, rel_h, rel_w,
                                                  kpad, vpad, wTq, wTk, wTv, rb);
    conv_kernel<<<448, 256, 0, stream>>>(x, wTq, wTk, wTv, qb, kb, vb,
                                         qbuf, kpad, vpad);
    attn_kernel<<<512, 256, 0, stream>>>(qbuf, kpad, vpad, rb, out);
}